// Round 5
// baseline (693.238 us; speedup 1.0000x reference)
//
#include <hip/hip_runtime.h>
#include <hip/hip_bf16.h>

// x: (4, 256, 32, 32, 32) fp32; qkv_weight: (512, 256); relative: (64, 63);
// gamma/beta: (512,). Output: (4, 256, 32, 32, 32) fp32.
//
// K0: split W fp32 -> Whi + Wlo bf16 (stored in stk2 region, dead until K2).
// K1: MFMA GEMM qkv = W @ x, 3-term bf16 split (fp32-equivalent precision).
//     NO LDS / NO BARRIERS: B-frags loaded direct global->reg (each x elem
//     has only 2 consumers in-block; L2 serves the re-read). W frags from
//     L2-resident Whi/Wlo. Output in Q2 layout:
//     Q2[b][w][head][tc][ch][i][tt]  (chunk-major per (b,w,head) block).
// K2: MFMA attention per (b,head,w); staging reads Q2 fully coalesced.
// K3: BN finalize + pair-sum, LDS transpose batched 4 i-rows/barrier.

typedef __attribute__((ext_vector_type(8))) short short8;
typedef __attribute__((ext_vector_type(16))) float f32x16;

__device__ inline unsigned short f2bu(float f) {
  __hip_bfloat16 h = __float2bfloat16(f);
  return *(unsigned short*)&h;
}

#define MFMA32(A, B, C) __builtin_amdgcn_mfma_f32_32x32x16_bf16(A, B, C, 0, 0, 0)

// K2 slab padding: [i][ch][tt]  addr = i*S_I + ch*S_C + tt
constexpr int S_I = 646;
constexpr int S_C = 10;

// ---------------- K0: W split fp32 -> bf16 hi/lo ----------------
__global__ __launch_bounds__(256) void k0_wsplit(
    const float* __restrict__ W, unsigned short* __restrict__ Whi,
    unsigned short* __restrict__ Wlo) {
  const int i = blockIdx.x * 256 + threadIdx.x;  // 512*256 = 131072 elems exactly
  const float w = W[i];
  const unsigned u = __float_as_uint(w);
  const float fhi = __uint_as_float(u & 0xFFFF0000u);
  const float lo = w - fhi;
  Whi[i] = (unsigned short)(u >> 16);
  Wlo[i] = (unsigned short)(__float_as_uint(lo) >> 16);
}

// ---------------- K1: MFMA QKV GEMM (direct-to-reg, no LDS) ----------------
__global__ __launch_bounds__(256) void k1_mfma(
    const unsigned short* __restrict__ Whi, const unsigned short* __restrict__ Wlo,
    const float* __restrict__ x, __hip_bfloat16* __restrict__ qkv) {
  const int td = threadIdx.x, bx = blockIdx.x;
  // otile adjacent -> x L2 temporal reuse across the 4 o-tiles of an n-strip
  const int otile = bx & 3, nt = (bx >> 2) & 255, b = bx >> 10;
  const int w = nt & 31, i0 = (nt >> 5) << 2;  // 4 consecutive i-rows
  const int o0 = otile * 128;
  const float* xb = x + (size_t)b * 256 * 32768;

  const int wid = td >> 6, l = td & 63, h = l >> 5, n = l & 31;
  const int wo = wid >> 1, wn = wid & 1;  // 2x2 waves over (o, c), 64x64 each

  // Column c = wn*64 + jt*32 + n maps to spatial
  //   (i0 + (n>>3))*1024 + w*32 + (wn*2+jt)*8 + (n&7)
  const int colsp0 = (i0 + (n >> 3)) * 1024 + w * 32 + (wn * 2) * 8 + (n & 7);
  // x pointers for jt=0/1 at k-range base h*8
  const float* px0 = xb + colsp0 + (size_t)(h * 8) * 32768;
  const float* px1 = px0 + 8;  // jt=1 -> tc+1 -> +8 dwords
  // W row pointers (lane n = o-row within 32-row group; k base h*8)
  const unsigned short* pwh = Whi + (size_t)(o0 + wo * 64 + n) * 256 + h * 8;
  const unsigned short* pwl = Wlo + (size_t)(o0 + wo * 64 + n) * 256 + h * 8;

  const f32x16 zf = {0, 0, 0, 0, 0, 0, 0, 0, 0, 0, 0, 0, 0, 0, 0, 0};
  f32x16 acc[2][2];
#pragma unroll
  for (int it = 0; it < 2; ++it)
#pragma unroll
    for (int jt = 0; jt < 2; ++jt) acc[it][jt] = zf;

#pragma unroll 4
  for (int kf = 0; kf < 16; ++kf) {  // K-step = 16 per MFMA
    // ---- loads (all independent; coalesced 32B runs per 8-lane group) ----
    const float* pk0 = px0 + (size_t)kf * 16 * 32768;
    const float* pk1 = px1 + (size_t)kf * 16 * 32768;
    float xv0[8], xv1[8];
#pragma unroll
    for (int e = 0; e < 8; ++e) {
      xv0[e] = pk0[(size_t)e * 32768];
      xv1[e] = pk1[(size_t)e * 32768];
    }
    short8 ahi[2], alo[2];
#pragma unroll
    for (int it = 0; it < 2; ++it) {
      ahi[it] = *(const short8*)(pwh + it * (32 * 256) + kf * 16);
      alo[it] = *(const short8*)(pwl + it * (32 * 256) + kf * 16);
    }
    // ---- split fp32 -> bf16 hi + residual-lo ----
    short8 bhi0, blo0, bhi1, blo1;
#pragma unroll
    for (int e = 0; e < 8; ++e) {
      const unsigned u0 = __float_as_uint(xv0[e]);
      bhi0[e] = (short)(u0 >> 16);
      blo0[e] = (short)(__float_as_uint(xv0[e] - __uint_as_float(u0 & 0xFFFF0000u)) >> 16);
      const unsigned u1 = __float_as_uint(xv1[e]);
      bhi1[e] = (short)(u1 >> 16);
      blo1[e] = (short)(__float_as_uint(xv1[e] - __uint_as_float(u1 & 0xFFFF0000u)) >> 16);
    }
    // ---- 12 MFMAs ----
#pragma unroll
    for (int it = 0; it < 2; ++it) {
      acc[it][0] = MFMA32(ahi[it], bhi0, acc[it][0]);
      acc[it][0] = MFMA32(ahi[it], blo0, acc[it][0]);
      acc[it][0] = MFMA32(alo[it], bhi0, acc[it][0]);
      acc[it][1] = MFMA32(ahi[it], bhi1, acc[it][1]);
      acc[it][1] = MFMA32(ahi[it], blo1, acc[it][1]);
      acc[it][1] = MFMA32(alo[it], bhi1, acc[it][1]);
    }
  }

  // Epilogue into Q2: addr = ((b*32+w)*8 + head)*65536 + tc*16384 + ch*256 + i0*8 + n
  // head = otile*2 + wo; tc = wn*2 + jt; ch = it*32 + (r&3)+8*(r>>2)+4*h.
  // 32 lanes (consecutive n) -> one full 64B line.
  __hip_bfloat16* qb2 = qkv + ((size_t)((b * 32 + w) * 8 + otile * 2 + wo)) * 65536 +
                        (size_t)(wn * 2) * 16384 + i0 * 8;
#pragma unroll
  for (int jt = 0; jt < 2; ++jt) {
    __hip_bfloat16* bjt = qb2 + jt * 16384;
#pragma unroll
    for (int it = 0; it < 2; ++it) {
#pragma unroll
      for (int r = 0; r < 16; ++r) {
        const int ch = it * 32 + (r & 3) + 8 * (r >> 2) + 4 * h;
        bjt[ch * 256 + n] = __float2bfloat16(acc[it][jt][r]);
      }
    }
  }
}

// ---------------- K2: MFMA attention (coalesced Q2 staging) ----------------
__global__ __launch_bounds__(256, 3) void k2_attn_mfma(
    const __hip_bfloat16* __restrict__ qkv, const float* __restrict__ rel,
    unsigned int* __restrict__ stk2, float* __restrict__ stats) {
  __shared__ __align__(16) __hip_bfloat16 slab[20672];      // [i][ch][tt] padded
  __shared__ __align__(16) unsigned short Sbuf[4 * 1280];   // per-wave sim [32][40] bf16
  __shared__ float statb[4][32][4];

  const int bx = blockIdx.x;
  const int w = bx & 31, head = (bx >> 5) & 7, b = bx >> 8;
  const int td = threadIdx.x;
  const int wid = td >> 6, l = td & 63, h = l >> 5, n = l & 31;

  short8 eqf[2], ekf[2], evf[4];
#pragma unroll
  for (int dt = 0; dt < 2; ++dt)
#pragma unroll
    for (int e = 0; e < 8; ++e) {
      int c = h * 8 + e, d = dt * 32 + n;
      eqf[dt][e] = (d < 63) ? (short)f2bu(rel[c * 63 + d]) : (short)0;
      ekf[dt][e] = (d < 63) ? (short)f2bu(rel[(16 + c) * 63 + d]) : (short)0;
    }
#pragma unroll
  for (int kh = 0; kh < 4; ++kh)
#pragma unroll
    for (int e = 0; e < 8; ++e) {
      int d = kh * 16 + h * 8 + e;
      evf[kh][e] = (d < 63) ? (short)f2bu(rel[(32 + n) * 63 + d]) : (short)0;
    }
  short8 ones;
#pragma unroll
  for (int e = 0; e < 8; ++e) ones[e] = (short)0x3F80;  // bf16 1.0

  // Q2 layout: block's data is 128 KB contiguous at ((b*32+w)*8+head)*65536
  const __hip_bfloat16* qbase = qkv + ((size_t)((b * 32 + w) * 8 + head)) * 65536;
  unsigned int* sb = stk2 + ((size_t)((b * 8 + head) * 32 + w)) * 32768;
  unsigned short* Sb = Sbuf + wid * 1280;

  const f32x16 zf = {0, 0, 0, 0, 0, 0, 0, 0, 0, 0, 0, 0, 0, 0, 0, 0};
  float st0 = 0, st1 = 0, st2 = 0, st3 = 0;

  for (int tc = 0; tc < 4; ++tc) {
    const int t0 = tc * 8;
    __syncthreads();  // previous chunk's readers done
    for (int r = 0; r < 8; ++r) {
      int idx = td + 256 * r;  // ch = idx>>5, i = idx&31
      const uint4 dat = *(const uint4*)(qbase + (size_t)tc * 16384 + (size_t)idx * 8);
      unsigned int* lp = (unsigned int*)(slab + (idx & 31) * S_I + (idx >> 5) * S_C);
      lp[0] = dat.x; lp[1] = dat.y; lp[2] = dat.z; lp[3] = dat.w;
    }
    __syncthreads();
    for (int u = 0; u < 2; ++u) {
      const int tt = 2 * wid + u;
      const int t = t0 + tt;
      short8 aq, ak;
#pragma unroll
      for (int e = 0; e < 8; ++e) {
        aq[e] = *(const short*)&slab[n * S_I + (h * 8 + e) * S_C + tt];
        ak[e] = *(const short*)&slab[n * S_I + (16 + h * 8 + e) * S_C + tt];
      }
      f32x16 qkD = MFMA32(aq, ak, zf);
      f32x16 Rq0 = MFMA32(aq, eqf[0], zf);
      f32x16 Rq1 = MFMA32(aq, eqf[1], zf);
      f32x16 Rk0 = MFMA32(ak, ekf[0], zf);
      f32x16 Rk1 = MFMA32(ak, ekf[1], zf);
#pragma unroll
      for (int r = 0; r < 16; ++r) {
        int rowr = (r & 3) + 8 * (r >> 2) + 4 * h;
        int d = rowr + n;
        int src = (d & 31) + 32 * h;
        float vq0 = __shfl(Rq0[r], src);
        float vq1 = __shfl(Rq1[r], src);
        float vk0 = __shfl(Rk0[r], src);
        float vk1 = __shfl(Rk1[r], src);
        float s = qkD[r] + (d < 32 ? vq0 + vk0 : vq1 + vk1);
        Sb[rowr * 40 + n] = f2bu(__expf(s));
      }
      short8 bv0, bv1;
#pragma unroll
      for (int e = 0; e < 8; ++e) {
        int j0 = h * 8 + e, j1 = 16 + h * 8 + e;
        bv0[e] = *(const short*)&slab[j0 * S_I + (32 + n) * S_C + tt];
        bv1[e] = *(const short*)&slab[j1 * S_I + (32 + n) * S_C + tt];
      }
      short8 as0 = *(const short8*)(Sb + n * 40 + h * 8);
      short8 as1 = *(const short8*)(Sb + n * 40 + 16 + h * 8);
      f32x16 svD = MFMA32(as1, bv1, MFMA32(as0, bv0, zf));
      f32x16 sumD = MFMA32(as1, ones, MFMA32(as0, ones, zf));
      f32x16 sveD = zf;
#pragma unroll
      for (int kh = 0; kh < 4; ++kh) {
        short8 ap;
#pragma unroll
        for (int e = 0; e < 8; ++e) {
          int k = kh * 16 + h * 8 + e;
          int jj = k - n;
          unsigned short raw = Sb[n * 40 + (jj & 31)];
          ap[e] = ((unsigned)jj < 32u) ? (short)raw : (short)0;
        }
        sveD = MFMA32(ap, evf[kh], sveD);
      }
#pragma unroll
      for (int r = 0; r < 16; ++r) {
        int rowr = (r & 3) + 8 * (r >> 2) + 4 * h;
        float inv = 1.0f / sumD[r];
        float svn = svD[r] * inv, sven = sveD[r] * inv;
        st0 += svn; st1 += svn * svn; st2 += sven; st3 += sven * sven;
        unsigned int pk = (unsigned int)f2bu(svn) | ((unsigned int)f2bu(sven) << 16);
        sb[((size_t)rowr * 32 + t) * 32 + n] = pk;
      }
    }
  }
  st0 += __shfl_xor(st0, 32); st1 += __shfl_xor(st1, 32);
  st2 += __shfl_xor(st2, 32); st3 += __shfl_xor(st3, 32);
  if (h == 0) {
    statb[wid][n][0] = st0; statb[wid][n][1] = st1;
    statb[wid][n][2] = st2; statb[wid][n][3] = st3;
  }
  __syncthreads();
  if (td < 32) {
    float a0 = 0, a1 = 0, a2 = 0, a3 = 0;
    for (int wv = 0; wv < 4; ++wv) {
      a0 += statb[wv][td][0]; a1 += statb[wv][td][1];
      a2 += statb[wv][td][2]; a3 += statb[wv][td][3];
    }
    const int o2 = head * 64 + 2 * td;
    atomicAdd(&stats[o2], a0);
    atomicAdd(&stats[o2 + 1], a2);
    atomicAdd(&stats[512 + o2], a1);
    atomicAdd(&stats[512 + o2 + 1], a3);
  }
}

// ---------------- K3: BN finalize + pair-sum, 4-row-batched LDS transpose ----------------
__global__ __launch_bounds__(256) void k3_finalize2(
    const unsigned int* __restrict__ stk2, const float* __restrict__ stats,
    const float* __restrict__ gamma, const float* __restrict__ beta,
    float* __restrict__ out) {
  __shared__ float trans[4][32][33];
  __shared__ float s_sc[64], s_sh[64];
  const int bx = blockIdx.x;
  const int w = bx & 31, head = (bx >> 5) & 7, b = bx >> 8;
  const int td = threadIdx.x;
  if (td < 64) {
    const int o2 = head * 64 + td;
    const float NINV = 1.f / 131072.f;
    float m = stats[o2] * NINV;
    float v = stats[512 + o2] * NINV - m * m;
    float sc = gamma[o2] * rsqrtf(v + 1e-5f);
    s_sc[td] = sc;
    s_sh[td] = beta[o2] - m * sc;
  }
  __syncthreads();
  const unsigned int* pb = stk2 + ((size_t)((b * 8 + head) * 32 + w)) * 32768;
  float* ob = out + ((size_t)(b * 256 + head * 32)) * 32768 + w * 32;
  const int t = td >> 3, c0 = (td & 7) * 4;
  const int t2 = td & 31, cbase = td >> 5;
  for (int i4 = 0; i4 < 32; i4 += 4) {
#pragma unroll
    for (int m = 0; m < 4; ++m) {
      const uint4 dat = *(const uint4*)(pb + (size_t)(i4 + m) * 1024 + td * 4);
      unsigned int dws[4] = {dat.x, dat.y, dat.z, dat.w};
#pragma unroll
      for (int q = 0; q < 4; ++q) {
        int c = c0 + q;
        float sv = __uint_as_float((dws[q] & 0xFFFFu) << 16);
        float sve = __uint_as_float(dws[q] & 0xFFFF0000u);
        trans[m][c][t] =
            sv * s_sc[2 * c] + sve * s_sc[2 * c + 1] + s_sh[2 * c] + s_sh[2 * c + 1];
      }
    }
    __syncthreads();
#pragma unroll
    for (int m = 0; m < 4; ++m) {
#pragma unroll
      for (int cc = 0; cc < 4; ++cc) {
        int c = cbase + 8 * cc;
        ob[(size_t)c * 32768 + (size_t)(i4 + m) * 1024 + t2] = trans[m][c][t2];
      }
    }
    __syncthreads();
  }
}

extern "C" void kernel_launch(void* const* d_in, const int* in_sizes, int n_in,
                              void* d_out, int out_size, void* d_ws, size_t ws_size,
                              hipStream_t stream) {
  const float* x        = (const float*)d_in[0];
  const float* qkv_w    = (const float*)d_in[1];
  const float* relative = (const float*)d_in[2];
  const float* gamma    = (const float*)d_in[3];
  const float* beta     = (const float*)d_in[4];
  float* out = (float*)d_out;

  __hip_bfloat16* qkv = (__hip_bfloat16*)d_ws;                              // 128 MB
  unsigned int* stk2 = (unsigned int*)((char*)d_ws + (size_t)134217728);    // 128 MB
  float* stats = (float*)((char*)d_ws + (size_t)268435456);                 // 4 KB
  // Whi/Wlo live in the stk2 region: dead until K2 writes it (stream-ordered).
  unsigned short* Whi = (unsigned short*)stk2;            // 256 KB
  unsigned short* Wlo = Whi + 131072;                     // 256 KB

  hipMemsetAsync(stats, 0, 1024 * sizeof(float), stream);
  k0_wsplit<<<dim3(512), dim3(256), 0, stream>>>(qkv_w, Whi, Wlo);
  k1_mfma<<<dim3(4096), dim3(256), 0, stream>>>(Whi, Wlo, x, qkv);
  k2_attn_mfma<<<dim3(1024), dim3(256), 0, stream>>>(qkv, relative, stk2, stats);
  k3_finalize2<<<dim3(1024), dim3(256), 0, stream>>>(stk2, stats, gamma, beta, out);
}

// Round 6
// 625.404 us; speedup vs baseline: 1.1085x; 1.1085x over previous
//
#include <hip/hip_runtime.h>
#include <hip/hip_bf16.h>

// x: (4, 256, 32, 32, 32) fp32; qkv_weight: (512, 256); relative: (64, 63);
// gamma/beta: (512,). Output: (4, 256, 32, 32, 32) fp32.
//
// K0: split W fp32 -> Whi + Wlo bf16 (stored in stk2 region, dead until K2).
// K1: MFMA GEMM qkv = W @ x, 3-term bf16 split (fp32-equivalent precision).
//     2-phase double-buffered LDS pipeline: STAGE(t+1) issued BEFORE compute(t),
//     one barrier per K-step -> staging HBM latency hidden under compute.
//     otile in HIGH bits of bx so the 4 blocks sharing an x-strip land on the
//     SAME XCD (bx siblings differ by 256 = 0 mod 8) -> L2 reuse works.
//     Output in Q2 layout: Q2[b][w][head][tc][ch][i][tt].
// K2: MFMA attention per (b,head,w); staging reads Q2 fully coalesced.
// K3: BN finalize + pair-sum, LDS transpose batched 4 i-rows/barrier.

typedef __attribute__((ext_vector_type(8))) short short8;
typedef __attribute__((ext_vector_type(16))) float f32x16;

__device__ inline unsigned short f2bu(float f) {
  __hip_bfloat16 h = __float2bfloat16(f);
  return *(unsigned short*)&h;
}

#define MFMA32(A, B, C) __builtin_amdgcn_mfma_f32_32x32x16_bf16(A, B, C, 0, 0, 0)

// K2 slab padding: [i][ch][tt]  addr = i*S_I + ch*S_C + tt
constexpr int S_I = 646;
constexpr int S_C = 10;

// ---------------- K0: W split fp32 -> bf16 hi/lo ----------------
__global__ __launch_bounds__(256) void k0_wsplit(
    const float* __restrict__ W, unsigned short* __restrict__ Whi,
    unsigned short* __restrict__ Wlo) {
  const int i = blockIdx.x * 256 + threadIdx.x;  // 512*256 = 131072 elems exactly
  const float w = W[i];
  const unsigned u = __float_as_uint(w);
  const float fhi = __uint_as_float(u & 0xFFFF0000u);
  const float lo = w - fhi;
  Whi[i] = (unsigned short)(u >> 16);
  Wlo[i] = (unsigned short)(__float_as_uint(lo) >> 16);
}

// ---------------- K1: MFMA QKV GEMM (2-phase dbuf LDS pipeline) ----------------
__device__ inline void gload16(const float* g, float* l) {
  __builtin_amdgcn_global_load_lds(
      (const __attribute__((address_space(1))) unsigned int*)(g),
      (__attribute__((address_space(3))) unsigned int*)(l), 16, 0, 0);
}

__global__ __launch_bounds__(256) void k1_mfma(
    const unsigned short* __restrict__ Whi, const unsigned short* __restrict__ Wlo,
    const float* __restrict__ x, __hip_bfloat16* __restrict__ qkv) {
  // Bs[buf][k][c] 32x128 fp32, local column c = (tc<<5)|(di<<3)|tt
  //   -> spatial = (i0+di)*1024 + w*32 + tc*8 + tt
  // Frag reads: 32 lanes read consecutive c within one k-row -> banks 0..31;
  // h=1 half reads +8 k-rows (+1024 dw == 0 mod 32) -> 2-way == free.
  __shared__ float Bs[2][32 * 128];  // 2 x 16 KB

  const int td = threadIdx.x, bx = blockIdx.x;
  // otile HIGH bits: siblings (same b,nt; otile 0..3) differ by 256 == 0 mod 8
  // -> same XCD -> x strip served by that XCD's L2.
  const int nt = bx & 255, otile = (bx >> 8) & 3, b = bx >> 10;
  const int w = nt & 31, i0 = (nt >> 5) << 2;  // 4 consecutive i-rows
  const int o0 = otile * 128;
  const float* xb = x + (size_t)b * 256 * 32768;

  const int wid = td >> 6, l = td & 63, h = l >> 5, n = l & 31;
  const int wo = wid >> 1, wn = wid & 1;  // 2x2 waves over (o, c), 64x64 each

  // staging address pieces (constant per thread across K-steps)
  const int sidx = td;  // plus r*256
  const f32x16 zf = {0, 0, 0, 0, 0, 0, 0, 0, 0, 0, 0, 0, 0, 0, 0, 0};
  f32x16 acc[2][2];
#pragma unroll
  for (int it = 0; it < 2; ++it)
#pragma unroll
    for (int jt = 0; jt < 2; ++jt) acc[it][jt] = zf;

#define STAGE_K1(K0, BUF)                                                         \
  {                                                                               \
    _Pragma("unroll") for (int r = 0; r < 4; ++r) {                               \
      const int idx = r * 256 + sidx;                                             \
      const int kk = idx >> 5, u = idx & 31;                                      \
      const int di = (u >> 1) & 3, tcq = u >> 3, toff = (u & 1) * 4;              \
      gload16(xb + (size_t)((K0) + kk) * 32768 + (i0 + di) * 1024 + w * 32 +      \
                  tcq * 8 + toff,                                                 \
              &Bs[BUF][idx * 4]);                                                 \
    }                                                                             \
  }

  STAGE_K1(0, 0);
  __syncthreads();  // drain prologue stage

  for (int step = 0; step < 8; ++step) {
    const int cur = step & 1;
    if (step < 7) STAGE_K1((step + 1) * 32, cur ^ 1);  // issue next tile FIRST
    const float* Bc = Bs[cur];
#pragma unroll
    for (int kf = 0; kf < 2; ++kf) {
      const int kbase = step * 32 + kf * 16 + h * 8;
      short8 ahi[2], alo[2];
#pragma unroll
      for (int it = 0; it < 2; ++it) {
        const int row = o0 + wo * 64 + it * 32 + n;
        ahi[it] = *(const short8*)(Whi + (size_t)row * 256 + kbase);
        alo[it] = *(const short8*)(Wlo + (size_t)row * 256 + kbase);
      }
      short8 bhi[2], blo[2];
#pragma unroll
      for (int jt = 0; jt < 2; ++jt) {
        const int col = wn * 64 + jt * 32 + n;
#pragma unroll
        for (int e = 0; e < 8; ++e) {
          const float f = Bc[(kf * 16 + h * 8 + e) * 128 + col];
          const unsigned u = __float_as_uint(f);
          bhi[jt][e] = (short)(u >> 16);
          const float fl = f - __uint_as_float(u & 0xFFFF0000u);
          blo[jt][e] = (short)(__float_as_uint(fl) >> 16);
        }
      }
#pragma unroll
      for (int it = 0; it < 2; ++it)
#pragma unroll
        for (int jt = 0; jt < 2; ++jt) {
          acc[it][jt] = MFMA32(ahi[it], bhi[jt], acc[it][jt]);
          acc[it][jt] = MFMA32(ahi[it], blo[jt], acc[it][jt]);
          acc[it][jt] = MFMA32(alo[it], bhi[jt], acc[it][jt]);
        }
    }
    __syncthreads();  // single barrier/K-step: drains next-tile vmcnt + my lgkm
  }
#undef STAGE_K1

  // Epilogue into Q2: addr = ((b*32+w)*8 + head)*65536 + tc*16384 + ch*256 + i0*8 + n
  // head = otile*2 + wo; tc = wn*2 + jt; ch = it*32 + (r&3)+8*(r>>2)+4*h.
  // 32 lanes (consecutive n) -> one full 64B line.
  __hip_bfloat16* qb2 = qkv + ((size_t)((b * 32 + w) * 8 + otile * 2 + wo)) * 65536 +
                        (size_t)(wn * 2) * 16384 + i0 * 8;
#pragma unroll
  for (int jt = 0; jt < 2; ++jt) {
    __hip_bfloat16* bjt = qb2 + jt * 16384;
#pragma unroll
    for (int it = 0; it < 2; ++it) {
#pragma unroll
      for (int r = 0; r < 16; ++r) {
        const int ch = it * 32 + (r & 3) + 8 * (r >> 2) + 4 * h;
        bjt[ch * 256 + n] = __float2bfloat16(acc[it][jt][r]);
      }
    }
  }
}

// ---------------- K2: MFMA attention (coalesced Q2 staging) ----------------
__global__ __launch_bounds__(256, 3) void k2_attn_mfma(
    const __hip_bfloat16* __restrict__ qkv, const float* __restrict__ rel,
    unsigned int* __restrict__ stk2, float* __restrict__ stats) {
  __shared__ __align__(16) __hip_bfloat16 slab[20672];      // [i][ch][tt] padded
  __shared__ __align__(16) unsigned short Sbuf[4 * 1280];   // per-wave sim [32][40] bf16
  __shared__ float statb[4][32][4];

  const int bx = blockIdx.x;
  const int w = bx & 31, head = (bx >> 5) & 7, b = bx >> 8;
  const int td = threadIdx.x;
  const int wid = td >> 6, l = td & 63, h = l >> 5, n = l & 31;

  short8 eqf[2], ekf[2], evf[4];
#pragma unroll
  for (int dt = 0; dt < 2; ++dt)
#pragma unroll
    for (int e = 0; e < 8; ++e) {
      int c = h * 8 + e, d = dt * 32 + n;
      eqf[dt][e] = (d < 63) ? (short)f2bu(rel[c * 63 + d]) : (short)0;
      ekf[dt][e] = (d < 63) ? (short)f2bu(rel[(16 + c) * 63 + d]) : (short)0;
    }
#pragma unroll
  for (int kh = 0; kh < 4; ++kh)
#pragma unroll
    for (int e = 0; e < 8; ++e) {
      int d = kh * 16 + h * 8 + e;
      evf[kh][e] = (d < 63) ? (short)f2bu(rel[(32 + n) * 63 + d]) : (short)0;
    }
  short8 ones;
#pragma unroll
  for (int e = 0; e < 8; ++e) ones[e] = (short)0x3F80;  // bf16 1.0

  // Q2 layout: block's data is 128 KB contiguous at ((b*32+w)*8+head)*65536
  const __hip_bfloat16* qbase = qkv + ((size_t)((b * 32 + w) * 8 + head)) * 65536;
  unsigned int* sb = stk2 + ((size_t)((b * 8 + head) * 32 + w)) * 32768;
  unsigned short* Sb = Sbuf + wid * 1280;

  const f32x16 zf = {0, 0, 0, 0, 0, 0, 0, 0, 0, 0, 0, 0, 0, 0, 0, 0};
  float st0 = 0, st1 = 0, st2 = 0, st3 = 0;

  for (int tc = 0; tc < 4; ++tc) {
    const int t0 = tc * 8;
    __syncthreads();  // previous chunk's readers done
    for (int r = 0; r < 8; ++r) {
      int idx = td + 256 * r;  // ch = idx>>5, i = idx&31
      const uint4 dat = *(const uint4*)(qbase + (size_t)tc * 16384 + (size_t)idx * 8);
      unsigned int* lp = (unsigned int*)(slab + (idx & 31) * S_I + (idx >> 5) * S_C);
      lp[0] = dat.x; lp[1] = dat.y; lp[2] = dat.z; lp[3] = dat.w;
    }
    __syncthreads();
    for (int u = 0; u < 2; ++u) {
      const int tt = 2 * wid + u;
      const int t = t0 + tt;
      short8 aq, ak;
#pragma unroll
      for (int e = 0; e < 8; ++e) {
        aq[e] = *(const short*)&slab[n * S_I + (h * 8 + e) * S_C + tt];
        ak[e] = *(const short*)&slab[n * S_I + (16 + h * 8 + e) * S_C + tt];
      }
      f32x16 qkD = MFMA32(aq, ak, zf);
      f32x16 Rq0 = MFMA32(aq, eqf[0], zf);
      f32x16 Rq1 = MFMA32(aq, eqf[1], zf);
      f32x16 Rk0 = MFMA32(ak, ekf[0], zf);
      f32x16 Rk1 = MFMA32(ak, ekf[1], zf);
#pragma unroll
      for (int r = 0; r < 16; ++r) {
        int rowr = (r & 3) + 8 * (r >> 2) + 4 * h;
        int d = rowr + n;
        int src = (d & 31) + 32 * h;
        float vq0 = __shfl(Rq0[r], src);
        float vq1 = __shfl(Rq1[r], src);
        float vk0 = __shfl(Rk0[r], src);
        float vk1 = __shfl(Rk1[r], src);
        float s = qkD[r] + (d < 32 ? vq0 + vk0 : vq1 + vk1);
        Sb[rowr * 40 + n] = f2bu(__expf(s));
      }
      short8 bv0, bv1;
#pragma unroll
      for (int e = 0; e < 8; ++e) {
        int j0 = h * 8 + e, j1 = 16 + h * 8 + e;
        bv0[e] = *(const short*)&slab[j0 * S_I + (32 + n) * S_C + tt];
        bv1[e] = *(const short*)&slab[j1 * S_I + (32 + n) * S_C + tt];
      }
      short8 as0 = *(const short8*)(Sb + n * 40 + h * 8);
      short8 as1 = *(const short8*)(Sb + n * 40 + 16 + h * 8);
      f32x16 svD = MFMA32(as1, bv1, MFMA32(as0, bv0, zf));
      f32x16 sumD = MFMA32(as1, ones, MFMA32(as0, ones, zf));
      f32x16 sveD = zf;
#pragma unroll
      for (int kh = 0; kh < 4; ++kh) {
        short8 ap;
#pragma unroll
        for (int e = 0; e < 8; ++e) {
          int k = kh * 16 + h * 8 + e;
          int jj = k - n;
          unsigned short raw = Sb[n * 40 + (jj & 31)];
          ap[e] = ((unsigned)jj < 32u) ? (short)raw : (short)0;
        }
        sveD = MFMA32(ap, evf[kh], sveD);
      }
#pragma unroll
      for (int r = 0; r < 16; ++r) {
        int rowr = (r & 3) + 8 * (r >> 2) + 4 * h;
        float inv = 1.0f / sumD[r];
        float svn = svD[r] * inv, sven = sveD[r] * inv;
        st0 += svn; st1 += svn * svn; st2 += sven; st3 += sven * sven;
        unsigned int pk = (unsigned int)f2bu(svn) | ((unsigned int)f2bu(sven) << 16);
        sb[((size_t)rowr * 32 + t) * 32 + n] = pk;
      }
    }
  }
  st0 += __shfl_xor(st0, 32); st1 += __shfl_xor(st1, 32);
  st2 += __shfl_xor(st2, 32); st3 += __shfl_xor(st3, 32);
  if (h == 0) {
    statb[wid][n][0] = st0; statb[wid][n][1] = st1;
    statb[wid][n][2] = st2; statb[wid][n][3] = st3;
  }
  __syncthreads();
  if (td < 32) {
    float a0 = 0, a1 = 0, a2 = 0, a3 = 0;
    for (int wv = 0; wv < 4; ++wv) {
      a0 += statb[wv][td][0]; a1 += statb[wv][td][1];
      a2 += statb[wv][td][2]; a3 += statb[wv][td][3];
    }
    const int o2 = head * 64 + 2 * td;
    atomicAdd(&stats[o2], a0);
    atomicAdd(&stats[o2 + 1], a2);
    atomicAdd(&stats[512 + o2], a1);
    atomicAdd(&stats[512 + o2 + 1], a3);
  }
}

// ---------------- K3: BN finalize + pair-sum, 4-row-batched LDS transpose ----------------
__global__ __launch_bounds__(256) void k3_finalize2(
    const unsigned int* __restrict__ stk2, const float* __restrict__ stats,
    const float* __restrict__ gamma, const float* __restrict__ beta,
    float* __restrict__ out) {
  __shared__ float trans[4][32][33];
  __shared__ float s_sc[64], s_sh[64];
  const int bx = blockIdx.x;
  const int w = bx & 31, head = (bx >> 5) & 7, b = bx >> 8;
  const int td = threadIdx.x;
  if (td < 64) {
    const int o2 = head * 64 + td;
    const float NINV = 1.f / 131072.f;
    float m = stats[o2] * NINV;
    float v = stats[512 + o2] * NINV - m * m;
    float sc = gamma[o2] * rsqrtf(v + 1e-5f);
    s_sc[td] = sc;
    s_sh[td] = beta[o2] - m * sc;
  }
  __syncthreads();
  const unsigned int* pb = stk2 + ((size_t)((b * 8 + head) * 32 + w)) * 32768;
  float* ob = out + ((size_t)(b * 256 + head * 32)) * 32768 + w * 32;
  const int t = td >> 3, c0 = (td & 7) * 4;
  const int t2 = td & 31, cbase = td >> 5;
  for (int i4 = 0; i4 < 32; i4 += 4) {
#pragma unroll
    for (int m = 0; m < 4; ++m) {
      const uint4 dat = *(const uint4*)(pb + (size_t)(i4 + m) * 1024 + td * 4);
      unsigned int dws[4] = {dat.x, dat.y, dat.z, dat.w};
#pragma unroll
      for (int q = 0; q < 4; ++q) {
        int c = c0 + q;
        float sv = __uint_as_float((dws[q] & 0xFFFFu) << 16);
        float sve = __uint_as_float(dws[q] & 0xFFFF0000u);
        trans[m][c][t] =
            sv * s_sc[2 * c] + sve * s_sc[2 * c + 1] + s_sh[2 * c] + s_sh[2 * c + 1];
      }
    }
    __syncthreads();
#pragma unroll
    for (int m = 0; m < 4; ++m) {
#pragma unroll
      for (int cc = 0; cc < 4; ++cc) {
        int c = cbase + 8 * cc;
        ob[(size_t)c * 32768 + (size_t)(i4 + m) * 1024 + t2] = trans[m][c][t2];
      }
    }
    __syncthreads();
  }
}

extern "C" void kernel_launch(void* const* d_in, const int* in_sizes, int n_in,
                              void* d_out, int out_size, void* d_ws, size_t ws_size,
                              hipStream_t stream) {
  const float* x        = (const float*)d_in[0];
  const float* qkv_w    = (const float*)d_in[1];
  const float* relative = (const float*)d_in[2];
  const float* gamma    = (const float*)d_in[3];
  const float* beta     = (const float*)d_in[4];
  float* out = (float*)d_out;

  __hip_bfloat16* qkv = (__hip_bfloat16*)d_ws;                              // 128 MB
  unsigned int* stk2 = (unsigned int*)((char*)d_ws + (size_t)134217728);    // 128 MB
  float* stats = (float*)((char*)d_ws + (size_t)268435456);                 // 4 KB
  // Whi/Wlo live in the stk2 region: dead until K2 writes it (stream-ordered).
  unsigned short* Whi = (unsigned short*)stk2;            // 256 KB
  unsigned short* Wlo = Whi + 131072;                     // 256 KB

  hipMemsetAsync(stats, 0, 1024 * sizeof(float), stream);
  k0_wsplit<<<dim3(512), dim3(256), 0, stream>>>(qkv_w, Whi, Wlo);
  k1_mfma<<<dim3(4096), dim3(256), 0, stream>>>(Whi, Wlo, x, qkv);
  k2_attn_mfma<<<dim3(1024), dim3(256), 0, stream>>>(qkv, relative, stk2, stats);
  k3_finalize2<<<dim3(1024), dim3(256), 0, stream>>>(stk2, stats, gamma, beta, out);
}